// Round 1
// baseline (2332.818 us; speedup 1.0000x reference)
//
#include <hip/hip_runtime.h>
#include <stdint.h>

typedef short bf16x8 __attribute__((ext_vector_type(8)));
typedef float f32x4 __attribute__((ext_vector_type(4)));

#define NROWS 50000
#define BATCH 32
#define SEQ 256
#define DIN 768
#define DMODEL 1024
#define NTOPK 5

__device__ inline unsigned short f2bf(float f) {
  union { float f; unsigned u; } x; x.f = f;
  unsigned u = x.u;
  unsigned r = u + 0x7fffu + ((u >> 16) & 1u);
  return (unsigned short)(r >> 16);
}
__device__ inline float bf2f(unsigned short h) {
  union { unsigned u; float f; } x; x.u = ((unsigned)h) << 16; return x.f;
}

// ---------------- convert fp32 -> bf16 ----------------
__global__ void k_f32_to_bf16(const float* __restrict__ in, unsigned short* __restrict__ out, int n) {
  int i = (blockIdx.x * blockDim.x + threadIdx.x) * 4;
  int stride = gridDim.x * blockDim.x * 4;
  for (; i < n; i += stride) {
    float4 f = *(const float4*)(in + i);
    ushort4 o;
    o.x = f2bf(f.x); o.y = f2bf(f.y); o.z = f2bf(f.z); o.w = f2bf(f.w);
    *(ushort4*)(out + i) = o;
  }
}

// ---------------- mean over sequence ----------------
__global__ void k_mean_hidden(const float* __restrict__ hidden, float* __restrict__ hm) {
  int b = blockIdx.x;
  int i = threadIdx.x; // 768 threads
  const float* p = hidden + (size_t)b * SEQ * DIN + i;
  float s = 0.f;
  for (int t = 0; t < SEQ; ++t) s += p[t * DIN];
  hm[b * DIN + i] = s * (1.0f / SEQ);
}

// ---------------- small fp32 GEMM: C[M,N] = A[M,K] @ W[N,K]^T + beta*bias ----------------
__global__ void k_sgemm_wt(const float* __restrict__ A, const float* __restrict__ W,
                           const float* __restrict__ bias, float* __restrict__ C,
                           int M, int N, int K, float beta) {
  __shared__ float A_l[32][65];
  __shared__ float W_l[64][65];
  int tid = threadIdx.x;            // 256
  int tx = tid & 63, ty = tid >> 6; // ty = wave
  int n0 = blockIdx.x * 64, m0 = blockIdx.y * 32;
  float acc[8] = {0.f,0.f,0.f,0.f,0.f,0.f,0.f,0.f};
  for (int k0 = 0; k0 < K; k0 += 64) {
    #pragma unroll
    for (int i = 0; i < 8; ++i) {
      int idx = tid + 256 * i; int r = idx >> 6, c = idx & 63;
      A_l[r][c] = A[(size_t)(m0 + r) * K + k0 + c];
    }
    #pragma unroll
    for (int i = 0; i < 16; ++i) {
      int idx = tid + 256 * i; int r = idx >> 6, c = idx & 63;
      W_l[r][c] = W[(size_t)(n0 + r) * K + k0 + c];
    }
    __syncthreads();
    for (int kk = 0; kk < 64; ++kk) {
      float wv = W_l[tx][kk];
      #pragma unroll
      for (int r = 0; r < 8; ++r) acc[r] += A_l[ty * 8 + r][kk] * wv;
    }
    __syncthreads();
  }
  float bv = bias[n0 + tx] * beta;
  #pragma unroll
  for (int r = 0; r < 8; ++r) C[(size_t)(m0 + ty * 8 + r) * N + n0 + tx] = acc[r] + bv;
}

// ---------------- bf16 MFMA GEMM: C[M,N](bf16) = A[M,K]bf16 @ W[N,K]bf16^T + bias ----------------
__global__ __launch_bounds__(256) void k_bf16_gemm(const unsigned short* __restrict__ A,
    const unsigned short* __restrict__ W, const float* __restrict__ bias,
    unsigned short* __restrict__ C, int M, int N, int K) {
  __shared__ unsigned short As[128][32];
  __shared__ unsigned short Ws[128][32];
  int tid = threadIdx.x;
  int wave = tid >> 6, lane = tid & 63;
  int wr = wave >> 1, wc = wave & 1;
  int bm = blockIdx.y * 128, bn = blockIdx.x * 128;
  f32x4 acc[4][4] = {};
  for (int k0 = 0; k0 < K; k0 += 32) {
    #pragma unroll
    for (int i = 0; i < 2; ++i) {
      int c = tid + 256 * i;
      int r = c >> 2, q = c & 3;
      *(uint4*)(&As[r][q * 8]) = *(const uint4*)(A + (size_t)(bm + r) * K + k0 + q * 8);
      *(uint4*)(&Ws[r][q * 8]) = *(const uint4*)(W + (size_t)(bn + r) * K + k0 + q * 8);
    }
    __syncthreads();
    bf16x8 af[4], bfr[4];
    #pragma unroll
    for (int mi = 0; mi < 4; ++mi)
      af[mi] = *(const bf16x8*)(&As[wr * 64 + mi * 16 + (lane & 15)][(lane >> 4) * 8]);
    #pragma unroll
    for (int ni = 0; ni < 4; ++ni)
      bfr[ni] = *(const bf16x8*)(&Ws[wc * 64 + ni * 16 + (lane & 15)][(lane >> 4) * 8]);
    #pragma unroll
    for (int mi = 0; mi < 4; ++mi)
      #pragma unroll
      for (int ni = 0; ni < 4; ++ni)
        acc[mi][ni] = __builtin_amdgcn_mfma_f32_16x16x32_bf16(af[mi], bfr[ni], acc[mi][ni], 0, 0, 0);
    __syncthreads();
  }
  #pragma unroll
  for (int ni = 0; ni < 4; ++ni) {
    int col = bn + wc * 64 + ni * 16 + (lane & 15);
    float bv = bias[col];
    #pragma unroll
    for (int mi = 0; mi < 4; ++mi) {
      #pragma unroll
      for (int j = 0; j < 4; ++j) {
        int row = bm + wr * 64 + mi * 16 + (lane >> 4) * 4 + j;
        C[(size_t)row * N + col] = f2bf(acc[mi][ni][j] + bv);
      }
    }
  }
}

// ---------------- retrieval dots: keys[b][i] = dot(vecs[b], table[i]) / ||table[i]|| ----------------
// pass1: also computes inv_tn[i] = 1/max(||t_i||, 1e-6)
__global__ __launch_bounds__(1024) void k_table_dots(const float* __restrict__ table,
    const float* __restrict__ vecs, float* __restrict__ keys,
    float* __restrict__ inv_tn, int pass1) {
  int tid = threadIdx.x;
  int b = tid & 31, p = tid >> 5;  // 32 batches x 32 k-parts
  int wave = tid >> 6, lane = tid & 63;
  float4 mreg[8];
  #pragma unroll
  for (int jj = 0; jj < 8; ++jj) mreg[jj] = *(const float4*)(vecs + b * DMODEL + p * 32 + jj * 4);
  __shared__ float red[16][4][32];
  __shared__ float redn[16][4];
  __shared__ float linv[4];
  for (int base = blockIdx.x * 4; base < NROWS; base += gridDim.x * 4) {
    float acc[4] = {0.f,0.f,0.f,0.f};
    float accn[4] = {0.f,0.f,0.f,0.f};
    #pragma unroll
    for (int r = 0; r < 4; ++r) {
      const float* row = table + (size_t)(base + r) * DMODEL + p * 32;
      #pragma unroll
      for (int jj = 0; jj < 8; ++jj) {
        float4 f = *(const float4*)(row + jj * 4);
        acc[r] += f.x * mreg[jj].x + f.y * mreg[jj].y + f.z * mreg[jj].z + f.w * mreg[jj].w;
        if (pass1) accn[r] += f.x * f.x + f.y * f.y + f.z * f.z + f.w * f.w;
      }
    }
    #pragma unroll
    for (int r = 0; r < 4; ++r) {
      float v = acc[r];
      v += __shfl_xor(v, 32);
      if (lane < 32) red[wave][r][lane] = v;
    }
    if (pass1) {
      #pragma unroll
      for (int r = 0; r < 4; ++r) {
        float vn = accn[r];
        vn += __shfl_xor(vn, 32);
        if (lane == 0) redn[wave][r] = vn;
      }
    }
    __syncthreads();
    if (pass1 && tid < 4) {
      float s = 0.f;
      #pragma unroll
      for (int w = 0; w < 16; ++w) s += redn[w][tid];
      float tn = sqrtf(s);
      float iv = 1.0f / fmaxf(tn, 1e-6f);
      inv_tn[base + tid] = iv;
      linv[tid] = iv;
    }
    __syncthreads();
    if (tid < 128) {
      int r = tid >> 5, bb = tid & 31;
      float s = 0.f;
      #pragma unroll
      for (int w = 0; w < 16; ++w) s += red[w][r][bb];
      float iv = pass1 ? linv[r] : inv_tn[base + r];
      keys[(size_t)bb * NROWS + base + r] = s * iv;
    }
    __syncthreads();
  }
}

// ---------------- top-K per batch (K<=5), ties -> lower index ----------------
__global__ void k_topk(const float* __restrict__ keys, int* __restrict__ out_idx, int K) {
  int b = blockIdx.x;
  int tid = threadIdx.x; // 1024
  const float* kb = keys + (size_t)b * NROWS;
  float tv[5]; int ti[5];
  #pragma unroll
  for (int j = 0; j < 5; ++j) { tv[j] = -3.4e38f; ti[j] = 0x7fffffff; }
  for (int i = tid; i < NROWS; i += 1024) {
    float v = kb[i];
    if (v > tv[4] || (v == tv[4] && i < ti[4])) {
      tv[4] = v; ti[4] = i;
      for (int j = 4; j > 0; --j) {
        bool sw = (tv[j] > tv[j-1]) || (tv[j] == tv[j-1] && ti[j] < ti[j-1]);
        if (!sw) break;
        float fv = tv[j]; tv[j] = tv[j-1]; tv[j-1] = fv;
        int iv = ti[j]; ti[j] = ti[j-1]; ti[j-1] = iv;
      }
    }
  }
  __shared__ float lv[1024 * 5];
  __shared__ int   li[1024 * 5];
  #pragma unroll
  for (int j = 0; j < 5; ++j) { lv[tid * 5 + j] = tv[j]; li[tid * 5 + j] = ti[j]; }
  __syncthreads();
  for (int off = 512; off >= 1; off >>= 1) {
    if (tid < off) {
      float av[5], bv[5]; int ai[5], bi[5];
      #pragma unroll
      for (int j = 0; j < 5; ++j) {
        av[j] = lv[tid * 5 + j]; ai[j] = li[tid * 5 + j];
        bv[j] = lv[(tid + off) * 5 + j]; bi[j] = li[(tid + off) * 5 + j];
      }
      int pa = 0, pb = 0;
      float mv[5]; int mi[5];
      #pragma unroll
      for (int j = 0; j < 5; ++j) {
        bool ta = (av[pa] > bv[pb]) || (av[pa] == bv[pb] && ai[pa] < bi[pb]);
        if (ta) { mv[j] = av[pa]; mi[j] = ai[pa]; ++pa; }
        else    { mv[j] = bv[pb]; mi[j] = bi[pb]; ++pb; }
      }
      #pragma unroll
      for (int j = 0; j < 5; ++j) { lv[tid * 5 + j] = mv[j]; li[tid * 5 + j] = mi[j]; }
    }
    __syncthreads();
  }
  if (tid == 0) {
    for (int j = 0; j < K; ++j) out_idx[b * K + j] = li[j];
  }
}

// ---------------- gathers ----------------
__global__ void k_gather_sel(const float* __restrict__ table, const int* __restrict__ best,
                             const float* __restrict__ inv_tn, float* __restrict__ sel) {
  int b = blockIdx.x, e = threadIdx.x; // 1024
  int idx = best[b];
  sel[b * DMODEL + e] = table[(size_t)idx * DMODEL + e] * inv_tn[idx];
}

__global__ void k_gather_targets(const float* __restrict__ table, const int* __restrict__ idx5,
                                 float* __restrict__ tg) {
  int bt = blockIdx.x, e = threadIdx.x; // 1024
  int idx = idx5[bt];
  tg[(size_t)bt * DMODEL + e] = table[(size_t)idx * DMODEL + e];
}

// ---------------- attention: one block per (b, t) ----------------
__global__ __launch_bounds__(256) void k_attention(const float* __restrict__ q,
    const unsigned short* __restrict__ kb, const unsigned short* __restrict__ vb,
    float* __restrict__ obuf) {
  int bt = blockIdx.x;
  int b = bt / NTOPK;
  int tid = threadIdx.x; // 256
  __shared__ float q_l[DMODEL];
  __shared__ float sc[4][SEQ];
  #pragma unroll
  for (int j = 0; j < 4; ++j) q_l[tid + 256 * j] = q[(size_t)bt * DMODEL + tid + 256 * j];
  __syncthreads();
  { // scores: thread = key position s
    int s = tid;
    const unsigned short* krow = kb + ((size_t)(b * SEQ + s)) * DMODEL;
    #pragma unroll
    for (int h = 0; h < 4; ++h) {
      float d = 0.f;
      for (int dd = 0; dd < 256; dd += 8) {
        uint4 pk = *(const uint4*)(krow + h * 256 + dd);
        const unsigned short* ph = (const unsigned short*)&pk;
        #pragma unroll
        for (int j2 = 0; j2 < 8; ++j2) d += bf2f(ph[j2]) * q_l[h * 256 + dd + j2];
      }
      sc[h][s] = d * 0.0625f; // 1/sqrt(256)
    }
  }
  __syncthreads();
  { // softmax: wave w handles head h=w
    int h = tid >> 6, lane = tid & 63;
    float vals[4];
    float mx = -3.4e38f;
    #pragma unroll
    for (int j = 0; j < 4; ++j) { vals[j] = sc[h][lane + 64 * j]; mx = fmaxf(mx, vals[j]); }
    #pragma unroll
    for (int o = 1; o < 64; o <<= 1) mx = fmaxf(mx, __shfl_xor(mx, o));
    float sum = 0.f;
    #pragma unroll
    for (int j = 0; j < 4; ++j) { vals[j] = expf(vals[j] - mx); sum += vals[j]; }
    #pragma unroll
    for (int o = 1; o < 64; o <<= 1) sum += __shfl_xor(sum, o);
    float rz = 1.0f / sum;
    #pragma unroll
    for (int j = 0; j < 4; ++j) sc[h][lane + 64 * j] = vals[j] * rz;
  }
  __syncthreads();
  { // PV: thread owns 4 contiguous output dims
    int h = tid >> 6;
    int e0 = tid * 4;
    float a0 = 0.f, a1 = 0.f, a2 = 0.f, a3 = 0.f;
    const unsigned short* vbase = vb + (size_t)(b * SEQ) * DMODEL + e0;
    for (int s = 0; s < SEQ; ++s) {
      float w = sc[h][s];
      ushort4 v4 = *(const ushort4*)(vbase + (size_t)s * DMODEL);
      a0 += w * bf2f(v4.x); a1 += w * bf2f(v4.y); a2 += w * bf2f(v4.z); a3 += w * bf2f(v4.w);
    }
    float* op = obuf + (size_t)bt * DMODEL + e0;
    op[0] = a0; op[1] = a1; op[2] = a2; op[3] = a3;
  }
}

// ---------------- sum over the 5 queries ----------------
__global__ void k_osum(const float* __restrict__ obuf, float* __restrict__ osum) {
  int g = blockIdx.x * blockDim.x + threadIdx.x; // 32768
  if (g >= BATCH * DMODEL) return;
  int b = g >> 10, e = g & 1023;
  float s = 0.f;
  #pragma unroll
  for (int t = 0; t < NTOPK; ++t) s += obuf[(size_t)(b * NTOPK + t) * DMODEL + e];
  osum[g] = s;
}

extern "C" void kernel_launch(void* const* d_in, const int* in_sizes, int n_in,
                              void* d_out, int out_size, void* d_ws, size_t ws_size,
                              hipStream_t stream) {
  const float* hidden = (const float*)d_in[0];
  const float* table  = (const float*)d_in[1];
  const float* fc1_w  = (const float*)d_in[2];
  const float* fc1_b  = (const float*)d_in[3];
  const float* q_w    = (const float*)d_in[4];
  const float* q_b    = (const float*)d_in[5];
  const float* k_w    = (const float*)d_in[6];
  const float* k_b    = (const float*)d_in[7];
  const float* v_w    = (const float*)d_in[8];
  const float* v_b    = (const float*)d_in[9];
  const float* out_w  = (const float*)d_in[10];
  const float* out_b  = (const float*)d_in[11];
  float* out = (float*)d_out;

  char* ws = (char*)d_ws;
  size_t off = 0;
  auto alloc = [&](size_t bytes) -> void* {
    void* p = ws + off;
    off += (bytes + 255) & ~(size_t)255;
    return p;
  };
  unsigned short* hid_bf  = (unsigned short*)alloc((size_t)BATCH * SEQ * DIN * 2);
  unsigned short* fc1w_bf = (unsigned short*)alloc((size_t)DMODEL * DIN * 2);
  unsigned short* kw_bf   = (unsigned short*)alloc((size_t)DMODEL * DMODEL * 2);
  unsigned short* vw_bf   = (unsigned short*)alloc((size_t)DMODEL * DMODEL * 2);
  unsigned short* x_bf    = (unsigned short*)alloc((size_t)BATCH * SEQ * DMODEL * 2);
  unsigned short* k_bf    = (unsigned short*)alloc((size_t)BATCH * SEQ * DMODEL * 2);
  unsigned short* v_bf    = (unsigned short*)alloc((size_t)BATCH * SEQ * DMODEL * 2);
  float* hm      = (float*)alloc((size_t)BATCH * DIN * 4);
  float* m       = (float*)alloc((size_t)BATCH * DMODEL * 4);
  float* sel     = (float*)alloc((size_t)BATCH * DMODEL * 4);
  float* keys    = (float*)alloc((size_t)BATCH * NROWS * 4);
  float* inv_tn  = (float*)alloc((size_t)NROWS * 4);
  int*   best    = (int*)alloc(BATCH * 4);
  int*   idx5    = (int*)alloc(BATCH * NTOPK * 4);
  float* targets = (float*)alloc((size_t)BATCH * NTOPK * DMODEL * 4);
  float* qbuf    = (float*)alloc((size_t)BATCH * NTOPK * DMODEL * 4);
  float* obuf    = (float*)alloc((size_t)BATCH * NTOPK * DMODEL * 4);
  float* osum    = (float*)alloc((size_t)BATCH * DMODEL * 4);
  (void)ws_size; (void)in_sizes; (void)n_in; (void)out_size;

  // converts to bf16
  k_f32_to_bf16<<<2048, 256, 0, stream>>>(hidden, hid_bf, BATCH * SEQ * DIN);
  k_f32_to_bf16<<<768, 256, 0, stream>>>(fc1_w, fc1w_bf, DMODEL * DIN);
  k_f32_to_bf16<<<1024, 256, 0, stream>>>(k_w, kw_bf, DMODEL * DMODEL);
  k_f32_to_bf16<<<1024, 256, 0, stream>>>(v_w, vw_bf, DMODEL * DMODEL);

  // exact-fp32 mean path: m = mean_s(hidden) @ fc1_w^T + fc1_b
  k_mean_hidden<<<32, 768, 0, stream>>>(hidden, hm);
  k_sgemm_wt<<<dim3(16, 1), 256, 0, stream>>>(hm, fc1_w, fc1_b, m, 32, DMODEL, DIN, 1.0f);

  // fc1: x (bf16)
  k_bf16_gemm<<<dim3(8, 64), 256, 0, stream>>>(hid_bf, fc1w_bf, fc1_b, x_bf, BATCH * SEQ, DMODEL, DIN);

  // retrieval pass 1: cos argmax
  k_table_dots<<<250, 1024, 0, stream>>>(table, m, keys, inv_tn, 1);
  k_topk<<<32, 1024, 0, stream>>>(keys, best, 1);
  k_gather_sel<<<32, 1024, 0, stream>>>(table, best, inv_tn, sel);

  // retrieval pass 2: top-5 by dot(sel, t_norm)
  k_table_dots<<<250, 1024, 0, stream>>>(table, sel, keys, inv_tn, 0);
  k_topk<<<32, 1024, 0, stream>>>(keys, idx5, NTOPK);
  k_gather_targets<<<160, 1024, 0, stream>>>(table, idx5, targets);

  // q projection (fp32, small M)
  k_sgemm_wt<<<dim3(16, 5), 256, 0, stream>>>(targets, q_w, q_b, qbuf, BATCH * NTOPK, DMODEL, DMODEL, 1.0f);

  // k, v projections (bf16 MFMA)
  k_bf16_gemm<<<dim3(8, 64), 256, 0, stream>>>(x_bf, kw_bf, k_b, k_bf, BATCH * SEQ, DMODEL, DMODEL);
  k_bf16_gemm<<<dim3(8, 64), 256, 0, stream>>>(x_bf, vw_bf, v_b, v_bf, BATCH * SEQ, DMODEL, DMODEL);

  // attention + sum over queries + output projection
  k_attention<<<160, 256, 0, stream>>>(qbuf, k_bf, v_bf, obuf);
  k_osum<<<128, 256, 0, stream>>>(obuf, osum);
  k_sgemm_wt<<<dim3(16, 1), 256, 0, stream>>>(osum, out_w, out_b, out, 32, DMODEL, DMODEL, 5.0f);
}